// Round 8
// baseline (114.085 us; speedup 1.0000x reference)
//
#include <hip/hip_runtime.h>
#include <hip/hip_bf16.h>
#include <stdint.h>

#define N_NODES 2048
#define FDIM 256

typedef short bf16x8 __attribute__((ext_vector_type(8)));   // 8 bf16 = 4 VGPRs (MFMA A/B frag)
typedef float f32x4 __attribute__((ext_vector_type(4)));
typedef unsigned short u16x4 __attribute__((ext_vector_type(4)));

static __device__ __forceinline__ unsigned short bf16r(float x) {
  __hip_bfloat16 h = __float2bfloat16(x);
  return __builtin_bit_cast(unsigned short, h);
}

// ---------------- k_prep: WT16 = bf16(W^T) [f][k]; wa1 = W@a1, wa2 = W@a2 (fp32) ---------------
__global__ __launch_bounds__(256) void k_prep(const float* __restrict__ W, const float* __restrict__ a,
                                              __hip_bfloat16* __restrict__ WT16,
                                              float* __restrict__ wa1, float* __restrict__ wa2) {
  int bid = blockIdx.x, t = threadIdx.x;
  if (bid < 16) {
    __shared__ __hip_bfloat16 T[64][67];
    int k0 = (bid & 3) * 64, f0 = (bid >> 2) * 64;
    int r = t >> 2, c0 = (t & 3) * 16;
    #pragma unroll
    for (int i = 0; i < 4; ++i) {
      f32x4 v = *(const f32x4*)(W + (size_t)(k0 + r) * FDIM + f0 + c0 + i * 4);
      #pragma unroll
      for (int j = 0; j < 4; ++j) T[r][c0 + i * 4 + j] = __float2bfloat16(v[j]);
    }
    __syncthreads();
    int fr = t >> 2, kc = (t & 3) * 16;
    unsigned short buf[16];
    #pragma unroll
    for (int i = 0; i < 16; ++i) buf[i] = __builtin_bit_cast(unsigned short, T[kc + i][fr]);
    uint4* dst = (uint4*)(WT16 + (size_t)(f0 + fr) * FDIM + k0 + kc);
    dst[0] = *(uint4*)&buf[0];
    dst[1] = *(uint4*)&buf[8];
  } else {
    int k = (bid - 16) * 64 + (t >> 2), q = t & 3;
    float s1 = 0.f, s2 = 0.f;
    #pragma unroll
    for (int i = 0; i < 16; ++i) {
      int f = q * 64 + i * 4;
      f32x4 w  = *(const f32x4*)(W + (size_t)k * FDIM + f);
      f32x4 v1 = *(const f32x4*)(a + f);
      f32x4 v2 = *(const f32x4*)(a + FDIM + f);
      #pragma unroll
      for (int j = 0; j < 4; ++j) { s1 += w[j] * v1[j]; s2 += w[j] * v2[j]; }
    }
    s1 += __shfl_xor(s1, 1); s1 += __shfl_xor(s1, 2);
    s2 += __shfl_xor(s2, 1); s2 += __shfl_xor(s2, 2);
    if (q == 0) { wa1[k] = s1; wa2[k] = s2; }
  }
}

// ---------------- k_h2: h = inp@W via MFMA; writes B-FRAGMENT layout Bf + e_src/e_dst ----------
// Bf[b][ft(16)][k0(64)][lane(64)][e(8)]: lane holds h[k = k0*32+(lane>>4)*8+e][f = ft*16+(lane&15)]
__global__ __launch_bounds__(256) void k_h2(const float* __restrict__ inp,
                                            const __hip_bfloat16* __restrict__ WT16,
                                            const float* __restrict__ wa1, const float* __restrict__ wa2,
                                            __hip_bfloat16* __restrict__ Bf,
                                            float* __restrict__ e_src, float* __restrict__ e_dst) {
  __shared__ char lds_raw[20480];
  __hip_bfloat16* Asm = (__hip_bfloat16*)lds_raw;  // [32][264] bf16
  int t = threadIdx.x;
  int r0 = blockIdx.x * 32;
  int b = r0 >> 11, j0 = r0 & (N_NODES - 1);
  {
    int r = t >> 3, q = t & 7, c0 = q * 32;
    const float* ip = inp + (size_t)(r0 + r) * FDIM + c0;
    float s1 = 0.f, s2 = 0.f;
    #pragma unroll
    for (int i = 0; i < 8; ++i) {
      f32x4 v  = *(const f32x4*)(ip + i * 4);
      f32x4 u1 = *(const f32x4*)(wa1 + c0 + i * 4);
      f32x4 u2 = *(const f32x4*)(wa2 + c0 + i * 4);
      u16x4 pk;
      #pragma unroll
      for (int j = 0; j < 4; ++j) {
        s1 += v[j] * u1[j];
        s2 += v[j] * u2[j];
        pk[j] = bf16r(v[j]);
      }
      *(u16x4*)(Asm + r * 264 + c0 + i * 4) = pk;
    }
    s1 += __shfl_xor(s1, 1); s1 += __shfl_xor(s1, 2); s1 += __shfl_xor(s1, 4);
    s2 += __shfl_xor(s2, 1); s2 += __shfl_xor(s2, 2); s2 += __shfl_xor(s2, 4);
    if (q == 0) { e_src[r0 + r] = s1; e_dst[r0 + r] = s2; }
  }
  __syncthreads();

  int lane = t & 63, wv = t >> 6, l15 = lane & 15, lq = lane >> 4;
  int f0 = wv * 64;
  f32x4 acc[2][4];
  #pragma unroll
  for (int mf = 0; mf < 2; ++mf)
    #pragma unroll
    for (int nf = 0; nf < 4; ++nf)
      #pragma unroll
      for (int e = 0; e < 4; ++e) acc[mf][nf][e] = 0.f;

  #pragma unroll
  for (int ks = 0; ks < 8; ++ks) {
    int k0 = ks * 32;
    bf16x8 af[2], bfr[4];
    #pragma unroll
    for (int mf = 0; mf < 2; ++mf)
      af[mf] = *(const bf16x8*)(Asm + (mf * 16 + l15) * 264 + k0 + lq * 8);
    #pragma unroll
    for (int nf = 0; nf < 4; ++nf)
      bfr[nf] = *(const bf16x8*)(WT16 + (size_t)(f0 + nf * 16 + l15) * FDIM + k0 + lq * 8);
    #pragma unroll
    for (int mf = 0; mf < 2; ++mf)
      #pragma unroll
      for (int nf = 0; nf < 4; ++nf)
        acc[mf][nf] = __builtin_amdgcn_mfma_f32_16x16x32_bf16(af[mf], bfr[nf], acc[mf][nf], 0, 0, 0);
  }

  __syncthreads();
  __hip_bfloat16* Tsm = (__hip_bfloat16*)lds_raw;  // [256][40] bf16: Tsm[f][j_local]
  #pragma unroll
  for (int mf = 0; mf < 2; ++mf)
    #pragma unroll
    for (int nf = 0; nf < 4; ++nf) {
      u16x4 pk;
      #pragma unroll
      for (int r = 0; r < 4; ++r) pk[r] = bf16r(acc[mf][nf][r]);
      int fl = f0 + nf * 16 + l15;
      int jl = mf * 16 + lq * 4;
      *(u16x4*)(Tsm + fl * 40 + jl) = pk;
    }
  __syncthreads();
  {
    int kt = j0 >> 5;                    // this block covers exactly one k0-block
    #pragma unroll
    for (int q = 0; q < 4; ++q) {
      int ft = (t >> 6) * 4 + q;
      // 8 bf16 from Tsm[ft*16 + (lane&15)][(lane>>4)*8 ..] (contiguous)
      uint4 v = *(const uint4*)(Tsm + (ft * 16 + l15) * 40 + lq * 8);
      *(uint4*)(Bf + ((((size_t)b * 16 + ft) * 64 + kt) * 64 + lane) * 8) = v;
    }
  }
}

// ---------------- k_mlp: softmax rows -> P in A-FRAGMENT layout --------------------------------
// Pf tile (b, it=i>>6): [k0(64)][sub(4)][lane(64)][e(8)];
// value P[i][j] -> sub=(i>>4)&3, lane=(((j>>3)&3)<<4)|(i&15), e=j&7, k0=j>>5.
__global__ __launch_bounds__(512) void k_mlp(const int* __restrict__ adj,
                                             const float* __restrict__ e_src,
                                             const float* __restrict__ e_dst,
                                             __hip_bfloat16* __restrict__ Pf) {
  int t = threadIdx.x, i = blockIdx.x;
  int b = t >> 6, l = t & 63;
  float es = e_src[(b << 11) + i];
  const float* edb = e_dst + ((size_t)b << 11);
  const int* arow = adj + (size_t)i * N_NODES;
  float ev[4][8];
  float mx = -3e38f;
  #pragma unroll
  for (int it = 0; it < 4; ++it) {
    int j0 = it * 512 + l * 8;
    int4 a0 = *(const int4*)(arow + j0);
    int4 a1 = *(const int4*)(arow + j0 + 4);
    f32x4 e0 = *(const f32x4*)(edb + j0);
    f32x4 e1 = *(const f32x4*)(edb + j0 + 4);
    const int* ap0 = (const int*)&a0;
    const int* ap1 = (const int*)&a1;
    #pragma unroll
    for (int c = 0; c < 4; ++c) {
      float s = es + e0[c];
      float lr = fmaxf(s, 0.01f * s);
      float e = (ap0[c] != 0) ? lr : -1e9f;
      ev[it][c] = e; mx = fmaxf(mx, e);
    }
    #pragma unroll
    for (int c = 0; c < 4; ++c) {
      float s = es + e1[c];
      float lr = fmaxf(s, 0.01f * s);
      float e = (ap1[c] != 0) ? lr : -1e9f;
      ev[it][c + 4] = e; mx = fmaxf(mx, e);
    }
  }
  #pragma unroll
  for (int m = 1; m <= 32; m <<= 1) mx = fmaxf(mx, __shfl_xor(mx, m));
  float sum = 0.f;
  #pragma unroll
  for (int it = 0; it < 4; ++it)
    #pragma unroll
    for (int c = 0; c < 8; ++c) {
      ev[it][c] = __expf(ev[it][c] - mx);
      sum += ev[it][c];
    }
  #pragma unroll
  for (int m = 1; m <= 32; m <<= 1) sum += __shfl_xor(sum, m);
  float il = 1.0f / sum;

  size_t tile_base = ((size_t)b * 32 + (i >> 6)) * 64 * 4 * 512;  // elems
  int sub = (i >> 4) & 3;
  int lane_lo = i & 15;
  #pragma unroll
  for (int it = 0; it < 4; ++it) {
    int k0 = it * 16 + (l >> 2);
    int lanep = ((l & 3) << 4) | lane_lo;
    unsigned short u[8];
    #pragma unroll
    for (int c = 0; c < 8; ++c) u[c] = bf16r(ev[it][c] * il);
    uint4 v;
    v.x = (uint32_t)u[0] | ((uint32_t)u[1] << 16);
    v.y = (uint32_t)u[2] | ((uint32_t)u[3] << 16);
    v.z = (uint32_t)u[4] | ((uint32_t)u[5] << 16);
    v.w = (uint32_t)u[6] | ((uint32_t)u[7] << 16);
    *(uint4*)(Pf + tile_base + ((size_t)(k0 * 4 + sub) * 64 + lanep) * 8) = v;
  }
}

// ---------------- k_pv: out = relu(P @ H), zero-LDS zero-barrier register streaming ------------
// grid 256 (b = bid&7 XCD-pinned, it = bid>>3), 512 thr / 8 waves (wm = wv>>2, wn = wv&3).
// wave output 32i x 64f; per K-step(32): 2 A-frag + 4 B-frag coalesced 16B loads + 8 MFMA.
struct Frags { bf16x8 a[2]; bf16x8 b[4]; };

__global__ __launch_bounds__(512) void k_pv(const __hip_bfloat16* __restrict__ Pf,
                                            const __hip_bfloat16* __restrict__ Bf,
                                            float* __restrict__ out) {
  int t = threadIdx.x;
  int b = blockIdx.x & 7;
  int it = blockIdx.x >> 3;
  int lane = t & 63, wv = t >> 6, l15 = lane & 15, lq = lane >> 4;
  int wm = wv >> 2, wn = wv & 3;

  const __hip_bfloat16* Abase = Pf + ((size_t)b * 32 + it) * (64 * 4 * 512) + (size_t)lane * 8;
  const __hip_bfloat16* Bbase = Bf + (size_t)b * (16 * 64 * 512) + (size_t)lane * 8;

  auto LOAD = [&](int k0) -> Frags {
    Frags f;
    #pragma unroll
    for (int mf = 0; mf < 2; ++mf)
      f.a[mf] = *(const bf16x8*)(Abase + ((size_t)k0 * 4 + (wm * 2 + mf)) * 512);
    #pragma unroll
    for (int nf = 0; nf < 4; ++nf)
      f.b[nf] = *(const bf16x8*)(Bbase + ((size_t)(wn * 4 + nf) * 64 + k0) * 512);
    return f;
  };

  f32x4 acc[2][4];
  #pragma unroll
  for (int mf = 0; mf < 2; ++mf)
    #pragma unroll
    for (int nf = 0; nf < 4; ++nf)
      #pragma unroll
      for (int e = 0; e < 4; ++e) acc[mf][nf][e] = 0.f;

  Frags f0 = LOAD(0);
  Frags f1 = LOAD(1);
  for (int k0 = 0; k0 < 64; k0 += 2) {
    Frags fn0 = LOAD(k0 + 2 < 64 ? k0 + 2 : 0);
    #pragma unroll
    for (int mf = 0; mf < 2; ++mf)
      #pragma unroll
      for (int nf = 0; nf < 4; ++nf)
        acc[mf][nf] = __builtin_amdgcn_mfma_f32_16x16x32_bf16(f0.a[mf], f0.b[nf], acc[mf][nf], 0, 0, 0);
    Frags fn1 = LOAD(k0 + 3 < 64 ? k0 + 3 : 0);
    #pragma unroll
    for (int mf = 0; mf < 2; ++mf)
      #pragma unroll
      for (int nf = 0; nf < 4; ++nf)
        acc[mf][nf] = __builtin_amdgcn_mfma_f32_16x16x32_bf16(f1.a[mf], f1.b[nf], acc[mf][nf], 0, 0, 0);
    f0 = fn0; f1 = fn1;
  }

  int i0 = it * 64;
  #pragma unroll
  for (int mf = 0; mf < 2; ++mf)
    #pragma unroll
    for (int nf = 0; nf < 4; ++nf)
      #pragma unroll
      for (int r = 0; r < 4; ++r) {
        int row = i0 + wm * 32 + mf * 16 + lq * 4 + r;
        int col = wn * 64 + nf * 16 + l15;
        out[((size_t)(b << 11) + row) * FDIM + col] = fmaxf(acc[mf][nf][r], 0.0f);
      }
}

// ====================== FALLBACK (small ws): round-2 proven path ===============================
__global__ __launch_bounds__(256) void k_h(const float* __restrict__ inp,
                                           const __hip_bfloat16* __restrict__ WT16,
                                           const float* __restrict__ wa1, const float* __restrict__ wa2,
                                           __hip_bfloat16* __restrict__ hT,
                                           float* __restrict__ e_src, float* __restrict__ e_dst) {
  __shared__ char lds_raw[20480];
  __hip_bfloat16* Asm = (__hip_bfloat16*)lds_raw;
  int t = threadIdx.x;
  int r0 = blockIdx.x * 32;
  int b = r0 >> 11, j0 = r0 & (N_NODES - 1);
  {
    int r = t >> 3, q = t & 7, c0 = q * 32;
    const float* ip = inp + (size_t)(r0 + r) * FDIM + c0;
    float s1 = 0.f, s2 = 0.f;
    #pragma unroll
    for (int i = 0; i < 8; ++i) {
      f32x4 v  = *(const f32x4*)(ip + i * 4);
      f32x4 u1 = *(const f32x4*)(wa1 + c0 + i * 4);
      f32x4 u2 = *(const f32x4*)(wa2 + c0 + i * 4);
      u16x4 pk;
      #pragma unroll
      for (int j = 0; j < 4; ++j) {
        s1 += v[j] * u1[j];
        s2 += v[j] * u2[j];
        pk[j] = bf16r(v[j]);
      }
      *(u16x4*)(Asm + r * 264 + c0 + i * 4) = pk;
    }
    s1 += __shfl_xor(s1, 1); s1 += __shfl_xor(s1, 2); s1 += __shfl_xor(s1, 4);
    s2 += __shfl_xor(s2, 1); s2 += __shfl_xor(s2, 2); s2 += __shfl_xor(s2, 4);
    if (q == 0) { e_src[r0 + r] = s1; e_dst[r0 + r] = s2; }
  }
  __syncthreads();

  int lane = t & 63, wv = t >> 6, l15 = lane & 15, lq = lane >> 4;
  int f0 = wv * 64;
  f32x4 acc[2][4];
  #pragma unroll
  for (int mf = 0; mf < 2; ++mf)
    #pragma unroll
    for (int nf = 0; nf < 4; ++nf)
      #pragma unroll
      for (int e = 0; e < 4; ++e) acc[mf][nf][e] = 0.f;

  #pragma unroll
  for (int ks = 0; ks < 8; ++ks) {
    int k0 = ks * 32;
    bf16x8 af[2], bfr[4];
    #pragma unroll
    for (int mf = 0; mf < 2; ++mf)
      af[mf] = *(const bf16x8*)(Asm + (mf * 16 + l15) * 264 + k0 + lq * 8);
    #pragma unroll
    for (int nf = 0; nf < 4; ++nf)
      bfr[nf] = *(const bf16x8*)(WT16 + (size_t)(f0 + nf * 16 + l15) * FDIM + k0 + lq * 8);
    #pragma unroll
    for (int mf = 0; mf < 2; ++mf)
      #pragma unroll
      for (int nf = 0; nf < 4; ++nf)
        acc[mf][nf] = __builtin_amdgcn_mfma_f32_16x16x32_bf16(af[mf], bfr[nf], acc[mf][nf], 0, 0, 0);
  }

  __syncthreads();
  __hip_bfloat16* Tsm = (__hip_bfloat16*)lds_raw;
  #pragma unroll
  for (int mf = 0; mf < 2; ++mf)
    #pragma unroll
    for (int nf = 0; nf < 4; ++nf) {
      u16x4 pk;
      #pragma unroll
      for (int r = 0; r < 4; ++r) pk[r] = bf16r(acc[mf][nf][r]);
      int fl = f0 + nf * 16 + l15;
      int jl = mf * 16 + lq * 4;
      *(u16x4*)(Tsm + fl * 40 + jl) = pk;
    }
  __syncthreads();
  {
    const uint4* src = (const uint4*)(Tsm + t * 40);
    uint4* dst = (uint4*)(hT + ((size_t)b * FDIM + t) * N_NODES + j0);
    dst[0] = src[0]; dst[1] = src[1]; dst[2] = src[2]; dst[3] = src[3];
  }
}

__global__ __launch_bounds__(256) void k_pack(const int* __restrict__ adj, uint32_t* __restrict__ adjp) {
  int t = threadIdx.x;
  int lane = t & 63;
  int i = blockIdx.x * 4 + (t >> 6);
  const int* row = adj + (size_t)i * N_NODES;
  #pragma unroll
  for (int it = 0; it < 32; ++it) {
    int v = row[it * 64 + lane];
    unsigned long long m = __ballot(v != 0);
    if (lane == 0) {
      adjp[i * 64 + it * 2]     = (uint32_t)(m & 0xffffffffull);
      adjp[i * 64 + it * 2 + 1] = (uint32_t)(m >> 32);
    }
  }
}

__global__ __launch_bounds__(256) void k_ml(const uint32_t* __restrict__ adjp,
                                            const float* __restrict__ e_src,
                                            const float* __restrict__ e_dst,
                                            float* __restrict__ mrow, float* __restrict__ ilrow) {
  int t = threadIdx.x;
  int lane = t & 63;
  int r = blockIdx.x * 4 + (t >> 6);
  int b = r >> 11, i = r & (N_NODES - 1);
  float es = e_src[r];
  const float* edb = e_dst + ((size_t)b << 11);
  const uint32_t* arow = adjp + (size_t)i * 64;
  float ev[32];
  float mx = -3e38f;
  #pragma unroll
  for (int it = 0; it < 32; ++it) {
    int j = it * 64 + lane;
    float ed = edb[j];
    uint32_t w = arow[j >> 5];
    float s = es + ed;
    float lr = fmaxf(s, 0.01f * s);
    float e = ((w >> (j & 31)) & 1u) ? lr : -1e9f;
    ev[it] = e;
    mx = fmaxf(mx, e);
  }
  #pragma unroll
  for (int m = 1; m <= 32; m <<= 1) mx = fmaxf(mx, __shfl_xor(mx, m));
  float sum = 0.f;
  #pragma unroll
  for (int it = 0; it < 32; ++it) sum += __expf(ev[it] - mx);
  #pragma unroll
  for (int m = 1; m <= 32; m <<= 1) sum += __shfl_xor(sum, m);
  if (lane == 0) { mrow[r] = mx; ilrow[r] = 1.0f / sum; }
}

__global__ __launch_bounds__(256) void k_pv_f(const __hip_bfloat16* __restrict__ hT,
                                              const uint32_t* __restrict__ adjp,
                                              const float* __restrict__ e_src,
                                              const float* __restrict__ e_dst,
                                              const float* __restrict__ mrow,
                                              const float* __restrict__ ilrow,
                                              float* __restrict__ out) {
  __shared__ __hip_bfloat16 Psm[2][64 * 40];
  int t = threadIdx.x;
  int bb = blockIdx.x & 7;
  int i0 = ((blockIdx.x >> 3) & 31) * 64;
  int fh = (blockIdx.x >> 8) * 128;
  int ip = t >> 2, jq = t & 3;
  int rflat = (bb << 11) + i0 + ip;
  float es = e_src[rflat], mi = mrow[rflat], ili = ilrow[rflat];
  const uint32_t* arow = adjp + (size_t)(i0 + ip) * 64;
  const float* edb = e_dst + ((size_t)bb << 11);
  const __hip_bfloat16* hTb = hT + (size_t)bb * FDIM * N_NODES;
  int lane = t & 63, wv = t >> 6, l15 = lane & 15, lq = lane >> 4;
  int wm = wv >> 1, wn = wv & 1;
  const __hip_bfloat16* bp[4];
  #pragma unroll
  for (int nf = 0; nf < 4; ++nf)
    bp[nf] = hTb + (size_t)(fh + wn * 64 + nf * 16 + l15) * N_NODES + lq * 8;

  auto computeP = [&](int js) -> uint4 {
    uint32_t word = arow[js >> 5] >> (jq * 8);
    f32x4 e0 = *(const f32x4*)(edb + js + jq * 8);
    f32x4 e1 = *(const f32x4*)(edb + js + jq * 8 + 4);
    unsigned short u[8];
    #pragma unroll
    for (int d = 0; d < 8; ++d) {
      float edv = (d < 4) ? e0[d] : e1[d & 3];
      float s = es + edv;
      float lr = fmaxf(s, 0.01f * s);
      float e = ((word >> d) & 1u) ? lr : -1e9f;
      u[d] = bf16r(__expf(e - mi) * ili);
    }
    uint4 r;
    r.x = (uint32_t)u[0] | ((uint32_t)u[1] << 16);
    r.y = (uint32_t)u[2] | ((uint32_t)u[3] << 16);
    r.z = (uint32_t)u[4] | ((uint32_t)u[5] << 16);
    r.w = (uint32_t)u[6] | ((uint32_t)u[7] << 16);
    return r;
  };

  f32x4 acc[2][4];
  #pragma unroll
  for (int mf = 0; mf < 2; ++mf)
    #pragma unroll
    for (int nf = 0; nf < 4; ++nf)
      #pragma unroll
      for (int e = 0; e < 4; ++e) acc[mf][nf][e] = 0.f;

  {
    uint4 p0 = computeP(0);
    *(uint4*)((char*)Psm[0] + ip * 80 + jq * 16) = p0;
  }
  bf16x8 bcur[4];
  #pragma unroll
  for (int nf = 0; nf < 4; ++nf) bcur[nf] = *(const bf16x8*)(bp[nf]);
  __syncthreads();

  int cur = 0;
  for (int js = 0; js < N_NODES; js += 32) {
    bf16x8 bn[4];
    bool more = (js + 32) < N_NODES;
    if (more) {
      #pragma unroll
      for (int nf = 0; nf < 4; ++nf) bn[nf] = *(const bf16x8*)(bp[nf] + js + 32);
      uint4 pn = computeP(js + 32);
      *(uint4*)((char*)Psm[cur ^ 1] + ip * 80 + jq * 16) = pn;
    }
    bf16x8 af[2];
    #pragma unroll
    for (int mf = 0; mf < 2; ++mf)
      af[mf] = *(const bf16x8*)((char*)Psm[cur] + (wm * 32 + mf * 16 + l15) * 80 + lq * 16);
    #pragma unroll
    for (int mf = 0; mf < 2; ++mf)
      #pragma unroll
      for (int nf = 0; nf < 4; ++nf)
        acc[mf][nf] = __builtin_amdgcn_mfma_f32_16x16x32_bf16(af[mf], bcur[nf], acc[mf][nf], 0, 0, 0);
    __syncthreads();
    if (more) {
      #pragma unroll
      for (int nf = 0; nf < 4; ++nf) bcur[nf] = bn[nf];
    }
    cur ^= 1;
  }

  #pragma unroll
  for (int mf = 0; mf < 2; ++mf)
    #pragma unroll
    for (int nf = 0; nf < 4; ++nf)
      #pragma unroll
      for (int r = 0; r < 4; ++r) {
        int row = i0 + wm * 32 + mf * 16 + lq * 4 + r;
        int col = fh + wn * 64 + nf * 16 + l15;
        out[((size_t)bb * N_NODES + row) * FDIM + col] = fmaxf(acc[mf][nf][r], 0.0f);
      }
}

extern "C" void kernel_launch(void* const* d_in, const int* in_sizes, int n_in,
                              void* d_out, int out_size, void* d_ws, size_t ws_size,
                              hipStream_t stream) {
  const float* inp = (const float*)d_in[0];
  const int*   adj = (const int*)d_in[1];
  const float* W   = (const float*)d_in[2];
  const float* a   = (const float*)d_in[3];
  float* out = (float*)d_out;
  char* ws = (char*)d_ws;

  const size_t NEED_BIG = 75761664ull;   // Pf 67.1MB + Bf 8.4MB + e/WT/wa
  if (ws_size >= NEED_BIG) {
    __hip_bfloat16* Pf   = (__hip_bfloat16*)ws;               // 67,108,864
    __hip_bfloat16* Bf   = (__hip_bfloat16*)(ws + 67108864);  //  8,388,608
    float* e_src         = (float*)(ws + 75497472);           //     65,536
    float* e_dst         = (float*)(ws + 75563008);           //     65,536
    __hip_bfloat16* WT16 = (__hip_bfloat16*)(ws + 75628544);  //    131,072
    float* wa1           = (float*)(ws + 75759616);           //      1,024
    float* wa2           = (float*)(ws + 75760640);           //      1,024

    k_prep<<<20, 256, 0, stream>>>(W, a, WT16, wa1, wa2);
    k_h2<<<512, 256, 0, stream>>>(inp, WT16, wa1, wa2, Bf, e_src, e_dst);
    k_mlp<<<2048, 512, 0, stream>>>(adj, e_src, e_dst, Pf);
    k_pv<<<256, 512, 0, stream>>>(Pf, Bf, out);
  } else {
    __hip_bfloat16* hT   = (__hip_bfloat16*)ws;
    uint32_t* adjp       = (uint32_t*)(ws + 8388608);
    float* e_src         = (float*)(ws + 8912896);
    float* e_dst         = (float*)(ws + 8978432);
    float* mrow          = (float*)(ws + 9043968);
    float* ilrow         = (float*)(ws + 9109504);
    __hip_bfloat16* WT16 = (__hip_bfloat16*)(ws + 9175040);
    float* wa1           = (float*)(ws + 9306112);
    float* wa2           = (float*)(ws + 9307136);

    k_pack<<<512, 256, 0, stream>>>(adj, adjp);
    k_prep<<<20, 256, 0, stream>>>(W, a, WT16, wa1, wa2);
    k_h<<<512, 256, 0, stream>>>(inp, WT16, wa1, wa2, hT, e_src, e_dst);
    k_ml<<<4096, 256, 0, stream>>>(adjp, e_src, e_dst, mrow, ilrow);
    k_pv_f<<<512, 256, 0, stream>>>(hT, adjp, e_src, e_dst, mrow, ilrow, out);
  }
}

// Round 9
// 101.774 us; speedup vs baseline: 1.1210x; 1.1210x over previous
//
#include <hip/hip_runtime.h>
#include <hip/hip_bf16.h>
#include <stdint.h>

#define N_NODES 2048
#define FDIM 256

typedef short bf16x8 __attribute__((ext_vector_type(8)));   // 8 bf16 = 4 VGPRs (MFMA A/B frag)
typedef float f32x4 __attribute__((ext_vector_type(4)));
typedef unsigned short u16x4 __attribute__((ext_vector_type(4)));

static __device__ __forceinline__ unsigned short bf16r(float x) {
  __hip_bfloat16 h = __float2bfloat16(x);
  return __builtin_bit_cast(unsigned short, h);
}

// ---------------- k_pack: adj int32 -> bitmask (adjp[i][w], bit j&31 of word j>>5) -------------
__global__ __launch_bounds__(256) void k_pack(const int* __restrict__ adj, uint32_t* __restrict__ adjp) {
  int t = threadIdx.x;
  int lane = t & 63;
  int i = blockIdx.x * 4 + (t >> 6);
  const int* row = adj + (size_t)i * N_NODES;
  #pragma unroll
  for (int it = 0; it < 32; ++it) {
    int v = row[it * 64 + lane];
    unsigned long long m = __ballot(v != 0);
    if (lane == 0) {
      adjp[i * 64 + it * 2]     = (uint32_t)(m & 0xffffffffull);
      adjp[i * 64 + it * 2 + 1] = (uint32_t)(m >> 32);
    }
  }
}

// ---------------- k_prep: WT16 = bf16(W^T) [f][k]; wa1 = W@a1, wa2 = W@a2 (fp32) ---------------
__global__ __launch_bounds__(256) void k_prep(const float* __restrict__ W, const float* __restrict__ a,
                                              __hip_bfloat16* __restrict__ WT16,
                                              float* __restrict__ wa1, float* __restrict__ wa2) {
  int bid = blockIdx.x, t = threadIdx.x;
  if (bid < 16) {
    __shared__ __hip_bfloat16 T[64][67];
    int k0 = (bid & 3) * 64, f0 = (bid >> 2) * 64;
    int r = t >> 2, c0 = (t & 3) * 16;
    #pragma unroll
    for (int i = 0; i < 4; ++i) {
      f32x4 v = *(const f32x4*)(W + (size_t)(k0 + r) * FDIM + f0 + c0 + i * 4);
      #pragma unroll
      for (int j = 0; j < 4; ++j) T[r][c0 + i * 4 + j] = __float2bfloat16(v[j]);
    }
    __syncthreads();
    int fr = t >> 2, kc = (t & 3) * 16;
    unsigned short buf[16];
    #pragma unroll
    for (int i = 0; i < 16; ++i) buf[i] = __builtin_bit_cast(unsigned short, T[kc + i][fr]);
    uint4* dst = (uint4*)(WT16 + (size_t)(f0 + fr) * FDIM + k0 + kc);
    dst[0] = *(uint4*)&buf[0];
    dst[1] = *(uint4*)&buf[8];
  } else {
    int k = (bid - 16) * 64 + (t >> 2), q = t & 3;
    float s1 = 0.f, s2 = 0.f;
    #pragma unroll
    for (int i = 0; i < 16; ++i) {
      int f = q * 64 + i * 4;
      f32x4 w  = *(const f32x4*)(W + (size_t)k * FDIM + f);
      f32x4 v1 = *(const f32x4*)(a + f);
      f32x4 v2 = *(const f32x4*)(a + FDIM + f);
      #pragma unroll
      for (int j = 0; j < 4; ++j) { s1 += w[j] * v1[j]; s2 += w[j] * v2[j]; }
    }
    s1 += __shfl_xor(s1, 1); s1 += __shfl_xor(s1, 2);
    s2 += __shfl_xor(s2, 1); s2 += __shfl_xor(s2, 2);
    if (q == 0) { wa1[k] = s1; wa2[k] = s2; }
  }
}

// ---------------- k_h2: h = inp@W via MFMA; writes B-FRAGMENT layout Bf + e_src/e_dst ----------
// Bf[b][ft(16)][k0(64)][lane(64)][e(8)]: lane holds h[k = k0*32+(lane>>4)*8+e][f = ft*16+(lane&15)]
__global__ __launch_bounds__(256) void k_h2(const float* __restrict__ inp,
                                            const __hip_bfloat16* __restrict__ WT16,
                                            const float* __restrict__ wa1, const float* __restrict__ wa2,
                                            __hip_bfloat16* __restrict__ Bf,
                                            float* __restrict__ e_src, float* __restrict__ e_dst) {
  __shared__ char lds_raw[20480];
  __hip_bfloat16* Asm = (__hip_bfloat16*)lds_raw;  // [32][264] bf16
  int t = threadIdx.x;
  int r0 = blockIdx.x * 32;
  int b = r0 >> 11, j0 = r0 & (N_NODES - 1);
  {
    int r = t >> 3, q = t & 7, c0 = q * 32;
    const float* ip = inp + (size_t)(r0 + r) * FDIM + c0;
    float s1 = 0.f, s2 = 0.f;
    #pragma unroll
    for (int i = 0; i < 8; ++i) {
      f32x4 v  = *(const f32x4*)(ip + i * 4);
      f32x4 u1 = *(const f32x4*)(wa1 + c0 + i * 4);
      f32x4 u2 = *(const f32x4*)(wa2 + c0 + i * 4);
      u16x4 pk;
      #pragma unroll
      for (int j = 0; j < 4; ++j) {
        s1 += v[j] * u1[j];
        s2 += v[j] * u2[j];
        pk[j] = bf16r(v[j]);
      }
      *(u16x4*)(Asm + r * 264 + c0 + i * 4) = pk;
    }
    s1 += __shfl_xor(s1, 1); s1 += __shfl_xor(s1, 2); s1 += __shfl_xor(s1, 4);
    s2 += __shfl_xor(s2, 1); s2 += __shfl_xor(s2, 2); s2 += __shfl_xor(s2, 4);
    if (q == 0) { e_src[r0 + r] = s1; e_dst[r0 + r] = s2; }
  }
  __syncthreads();

  int lane = t & 63, wv = t >> 6, l15 = lane & 15, lq = lane >> 4;
  int f0 = wv * 64;
  f32x4 acc[2][4];
  #pragma unroll
  for (int mf = 0; mf < 2; ++mf)
    #pragma unroll
    for (int nf = 0; nf < 4; ++nf)
      #pragma unroll
      for (int e = 0; e < 4; ++e) acc[mf][nf][e] = 0.f;

  #pragma unroll
  for (int ks = 0; ks < 8; ++ks) {
    int k0 = ks * 32;
    bf16x8 af[2], bfr[4];
    #pragma unroll
    for (int mf = 0; mf < 2; ++mf)
      af[mf] = *(const bf16x8*)(Asm + (mf * 16 + l15) * 264 + k0 + lq * 8);
    #pragma unroll
    for (int nf = 0; nf < 4; ++nf)
      bfr[nf] = *(const bf16x8*)(WT16 + (size_t)(f0 + nf * 16 + l15) * FDIM + k0 + lq * 8);
    #pragma unroll
    for (int mf = 0; mf < 2; ++mf)
      #pragma unroll
      for (int nf = 0; nf < 4; ++nf)
        acc[mf][nf] = __builtin_amdgcn_mfma_f32_16x16x32_bf16(af[mf], bfr[nf], acc[mf][nf], 0, 0, 0);
  }

  __syncthreads();
  __hip_bfloat16* Tsm = (__hip_bfloat16*)lds_raw;  // [256][40] bf16: Tsm[f][j_local]
  #pragma unroll
  for (int mf = 0; mf < 2; ++mf)
    #pragma unroll
    for (int nf = 0; nf < 4; ++nf) {
      u16x4 pk;
      #pragma unroll
      for (int r = 0; r < 4; ++r) pk[r] = bf16r(acc[mf][nf][r]);
      int fl = f0 + nf * 16 + l15;
      int jl = mf * 16 + lq * 4;
      *(u16x4*)(Tsm + fl * 40 + jl) = pk;
    }
  __syncthreads();
  {
    int kt = j0 >> 5;                    // this block covers exactly one k0-block
    #pragma unroll
    for (int q = 0; q < 4; ++q) {
      int ft = (t >> 6) * 4 + q;
      uint4 v = *(const uint4*)(Tsm + (ft * 16 + l15) * 40 + lq * 8);
      *(uint4*)(Bf + ((((size_t)b * 16 + ft) * 64 + kt) * 64 + lane) * 8) = v;
    }
  }
}

// ---------------- k_mlp2: fused softmax stats + P in A-FRAGMENT layout, coalesced writes -------
// block = (b = bid&7, it = bid>>3) -> 64-row P tile. Pass 1: wave wv owns rows wv*8..+8,
// computes m, 1/l. Pass 2: wave writes one contiguous 1KB fragment chunk per iteration.
// Chunk c = k0*4+sub holds P[i=sub*16+(l&15)][j=k0*32+(l>>4)*8+e], e=0..7.
__global__ __launch_bounds__(512) void k_mlp2(const uint32_t* __restrict__ adjp,
                                              const float* __restrict__ e_src,
                                              const float* __restrict__ e_dst,
                                              __hip_bfloat16* __restrict__ Pf) {
  __shared__ float sm_ed[2048];       // 8 KB
  __shared__ uint32_t sm_adj[4096];   // 16 KB: adjp rows i0..i0+64
  __shared__ float sm_es[64], sm_m[64], sm_il[64];
  int t = threadIdx.x;
  int b = blockIdx.x & 7, it = blockIdx.x >> 3;
  int i0 = it * 64;
  int lane = t & 63, wv = t >> 6;
  const float* edb = e_dst + ((size_t)b << 11);

  *(f32x4*)(sm_ed + t * 4) = *(const f32x4*)(edb + t * 4);
  {
    const uint4* src = (const uint4*)(adjp + i0 * 64 + t * 8);
    *(uint4*)(sm_adj + t * 8)     = src[0];
    *(uint4*)(sm_adj + t * 8 + 4) = src[1];
  }
  __syncthreads();

  // ---- pass 1: per-row max & inverse-sum (wave wv -> rows wv*8 .. +8)
  for (int rr = 0; rr < 8; ++rr) {
    int iloc = wv * 8 + rr;
    float es = e_src[(b << 11) + i0 + iloc];
    float ev[32];
    float mx = -3e38f;
    #pragma unroll
    for (int c = 0; c < 32; ++c) {
      int j = c * 64 + lane;
      float s = es + sm_ed[j];
      float lr = fmaxf(s, 0.01f * s);
      uint32_t w = sm_adj[iloc * 64 + (j >> 5)];
      float e = ((w >> (j & 31)) & 1u) ? lr : -1e9f;
      ev[c] = e;
      mx = fmaxf(mx, e);
    }
    #pragma unroll
    for (int m = 1; m <= 32; m <<= 1) mx = fmaxf(mx, __shfl_xor(mx, m));
    float sum = 0.f;
    #pragma unroll
    for (int c = 0; c < 32; ++c) sum += __expf(ev[c] - mx);
    #pragma unroll
    for (int m = 1; m <= 32; m <<= 1) sum += __shfl_xor(sum, m);
    if (lane == 0) { sm_es[iloc] = es; sm_m[iloc] = mx; sm_il[iloc] = 1.0f / sum; }
  }
  __syncthreads();

  // ---- pass 2: fragment-order emission, 1KB contiguous per wave per iter
  size_t tile_base = ((size_t)(b * 32 + it)) << 17;   // 131072 elems per tile
  int l15 = lane & 15, lq = lane >> 4;
  for (int cc = 0; cc < 32; ++cc) {
    int c = cc * 8 + wv;
    int k0 = c >> 2, sub = c & 3;
    int iloc = sub * 16 + l15;
    int j0 = k0 * 32 + lq * 8;
    float es = sm_es[iloc], mi = sm_m[iloc], ili = sm_il[iloc];
    uint32_t w = sm_adj[iloc * 64 + k0] >> (lq * 8);
    unsigned short u[8];
    #pragma unroll
    for (int e = 0; e < 8; ++e) {
      float s = es + sm_ed[j0 + e];
      float lr = fmaxf(s, 0.01f * s);
      float x = ((w >> e) & 1u) ? lr : -1e9f;
      u[e] = bf16r(__expf(x - mi) * ili);
    }
    uint4 v;
    v.x = (uint32_t)u[0] | ((uint32_t)u[1] << 16);
    v.y = (uint32_t)u[2] | ((uint32_t)u[3] << 16);
    v.z = (uint32_t)u[4] | ((uint32_t)u[5] << 16);
    v.w = (uint32_t)u[6] | ((uint32_t)u[7] << 16);
    *(uint4*)(Pf + tile_base + (size_t)c * 512 + lane * 8) = v;
  }
}

// ---------------- k_pv: out = relu(P @ H), zero-LDS zero-barrier register streaming ------------
// grid 256 (b = bid&7 XCD-pinned, it = bid>>3), 512 thr / 8 waves (wm = wv>>2, wn = wv&3).
struct Frags { bf16x8 a[2]; bf16x8 b[4]; };

__global__ __launch_bounds__(512) void k_pv(const __hip_bfloat16* __restrict__ Pf,
                                            const __hip_bfloat16* __restrict__ Bf,
                                            float* __restrict__ out) {
  int t = threadIdx.x;
  int b = blockIdx.x & 7;
  int it = blockIdx.x >> 3;
  int lane = t & 63, wv = t >> 6, l15 = lane & 15, lq = lane >> 4;
  int wm = wv >> 2, wn = wv & 3;

  const __hip_bfloat16* Abase = Pf + ((size_t)b * 32 + it) * (64 * 4 * 512) + (size_t)lane * 8;
  const __hip_bfloat16* Bbase = Bf + (size_t)b * (16 * 64 * 512) + (size_t)lane * 8;

  auto LOAD = [&](int k0) -> Frags {
    Frags f;
    #pragma unroll
    for (int mf = 0; mf < 2; ++mf)
      f.a[mf] = *(const bf16x8*)(Abase + ((size_t)k0 * 4 + (wm * 2 + mf)) * 512);
    #pragma unroll
    for (int nf = 0; nf < 4; ++nf)
      f.b[nf] = *(const bf16x8*)(Bbase + ((size_t)(wn * 4 + nf) * 64 + k0) * 512);
    return f;
  };

  f32x4 acc[2][4];
  #pragma unroll
  for (int mf = 0; mf < 2; ++mf)
    #pragma unroll
    for (int nf = 0; nf < 4; ++nf)
      #pragma unroll
      for (int e = 0; e < 4; ++e) acc[mf][nf][e] = 0.f;

  Frags f0 = LOAD(0);
  Frags f1 = LOAD(1);
  for (int k0 = 0; k0 < 64; k0 += 2) {
    Frags fn0 = LOAD(k0 + 2 < 64 ? k0 + 2 : 0);
    #pragma unroll
    for (int mf = 0; mf < 2; ++mf)
      #pragma unroll
      for (int nf = 0; nf < 4; ++nf)
        acc[mf][nf] = __builtin_amdgcn_mfma_f32_16x16x32_bf16(f0.a[mf], f0.b[nf], acc[mf][nf], 0, 0, 0);
    Frags fn1 = LOAD(k0 + 3 < 64 ? k0 + 3 : 0);
    #pragma unroll
    for (int mf = 0; mf < 2; ++mf)
      #pragma unroll
      for (int nf = 0; nf < 4; ++nf)
        acc[mf][nf] = __builtin_amdgcn_mfma_f32_16x16x32_bf16(f1.a[mf], f1.b[nf], acc[mf][nf], 0, 0, 0);
    f0 = fn0; f1 = fn1;
  }

  int i0 = it * 64;
  #pragma unroll
  for (int mf = 0; mf < 2; ++mf)
    #pragma unroll
    for (int nf = 0; nf < 4; ++nf)
      #pragma unroll
      for (int r = 0; r < 4; ++r) {
        int row = i0 + wm * 32 + mf * 16 + lq * 4 + r;
        int col = wn * 64 + nf * 16 + l15;
        out[((size_t)(b << 11) + row) * FDIM + col] = fmaxf(acc[mf][nf][r], 0.0f);
      }
}

extern "C" void kernel_launch(void* const* d_in, const int* in_sizes, int n_in,
                              void* d_out, int out_size, void* d_ws, size_t ws_size,
                              hipStream_t stream) {
  const float* inp = (const float*)d_in[0];
  const int*   adj = (const int*)d_in[1];
  const float* W   = (const float*)d_in[2];
  const float* a   = (const float*)d_in[3];
  float* out = (float*)d_out;
  char* ws = (char*)d_ws;

  __hip_bfloat16* Pf   = (__hip_bfloat16*)ws;               // 67,108,864
  __hip_bfloat16* Bf   = (__hip_bfloat16*)(ws + 67108864);  //  8,388,608
  float* e_src         = (float*)(ws + 75497472);           //     65,536
  float* e_dst         = (float*)(ws + 75563008);           //     65,536
  __hip_bfloat16* WT16 = (__hip_bfloat16*)(ws + 75628544);  //    131,072
  float* wa1           = (float*)(ws + 75759616);           //      1,024
  float* wa2           = (float*)(ws + 75760640);           //      1,024  -> end 75,761,664 (proven)

  // adjp (512 KB) lives in d_out: dead until k_pv fully overwrites out at the end.
  uint32_t* adjp = (uint32_t*)d_out;

  k_pack<<<512, 256, 0, stream>>>(adj, adjp);
  k_prep<<<20, 256, 0, stream>>>(W, a, WT16, wa1, wa2);
  k_h2<<<512, 256, 0, stream>>>(inp, WT16, wa1, wa2, Bf, e_src, e_dst);
  k_mlp2<<<256, 512, 0, stream>>>(adjp, e_src, e_dst, Pf);
  k_pv<<<256, 512, 0, stream>>>(Pf, Bf, out);
}